// Round 7
// baseline (317.599 us; speedup 1.0000x reference)
//
#include <hip/hip_runtime.h>
#include <hip/hip_bf16.h>
#include <hip/hip_cooperative_groups.h>

namespace cg = cooperative_groups;

// Graph message-passing layer, bf16 MFMA implementation, v7.
// vs v6: (1) GEMM2 reads each W2 fragment once per wave (h A-frags for both
// edge-groups held in registers); (2) hist/scan/reorder fused into one
// cooperative kernel; (3) agg-zero folded into prep_all; (4) e2 prefetched
// before weight staging. 4 dispatches total.
// N=10000 nodes, E=640000 edges, F=M=O=128.

#define NN 10000
#define NE 640000

typedef __attribute__((ext_vector_type(8))) short short8;
typedef __attribute__((ext_vector_type(4))) short short4v;
typedef __attribute__((ext_vector_type(4))) float floatx4;

__device__ __forceinline__ short f2bf(float f) {
    union { float f; unsigned u; } v; v.f = f;
    unsigned r = v.u + 0x7fffu + ((v.u >> 16) & 1u);   // RNE, NaN-free inputs
    return (short)(r >> 16);
}

__device__ __forceinline__ float sigmoidf_(float x) {
    return __builtin_amdgcn_rcpf(1.f + __expf(-x));
}
__device__ __forceinline__ float softsignf_(float x) {
    return x * __builtin_amdgcn_rcpf(1.f + fabsf(x));
}

// ---------- fused prep kernel ----------
// partitions: [0,1250) agg zero | [1250,2500) feat->bf16 | [2500,2628) Wm1 swz
// | [2628,2692) Wm2 swz | [2692,2884) Wf1 T | [2884,2948) Wf2 T
__global__ __launch_bounds__(256) void prep_all(
    const float* __restrict__ feat,
    const float* __restrict__ Wm1, const float* __restrict__ Wm2,
    const float* __restrict__ Wf1, const float* __restrict__ Wf2,
    float* __restrict__ agg, short* __restrict__ fbf, short* __restrict__ W12,
    short* __restrict__ Wf1T, short* __restrict__ Wf2T)
{
    const int bid = blockIdx.x, tid = threadIdx.x;
    if (bid < 1250) {                       // zero agg: 1,280,000 f32 = 320,000 f4
        int i = bid * 256 + tid;
        ((float4*)agg)[i] = make_float4(0.f, 0.f, 0.f, 0.f);
    } else if (bid < 2500) {                // features f32 -> bf16, 4/thread
        int i = (bid - 1250) * 256 + tid;   // n4 = 320000, exact
        float4 v = ((const float4*)feat)[i];
        short4v o;
        o[0] = f2bf(v.x); o[1] = f2bf(v.y); o[2] = f2bf(v.z); o[3] = f2bf(v.w);
        ((short4v*)fbf)[i] = o;
    } else if (bid < 2628) {                // Wm1 [256][128] -> swz [128][256]
        int i = (bid - 2500) * 256 + tid;   // 32768, exact
        int m = i >> 8, k = i & 255;
        W12[m * 256 + (k ^ ((m & 7) << 3))] = f2bf(Wm1[k * 128 + m]);
    } else if (bid < 2692) {                // Wm2 [128][128] -> swz
        int i = (bid - 2628) * 256 + tid;   // 16384, exact
        int m = i >> 7, k = i & 127;
        W12[32768 + m * 128 + (k ^ ((m & 7) << 3))] = f2bf(Wm2[k * 128 + m]);
    } else if (bid < 2884) {                // Wf1 [384][128] -> T [128][384]
        int i = (bid - 2692) * 256 + tid;   // 49152, exact
        int c = i / 384, k = i - c * 384;
        Wf1T[i] = f2bf(Wf1[k * 128 + c]);
    } else {                                // Wf2 [128][128] -> T
        int i = (bid - 2884) * 256 + tid;   // 16384, exact
        int c = i >> 7, k = i & 127;
        Wf2T[i] = f2bf(Wf2[k * 128 + c]);
    }
}

// ---------- fused counting sort (cooperative) ----------
// 256 blocks x 1024 threads = 262144 threads, grid-wide syncs between phases.
__global__ __launch_bounds__(1024) void sort_fused(
    const int* __restrict__ rows, const int* __restrict__ cols,
    int* __restrict__ counts, int* __restrict__ cursor,
    int* __restrict__ nodeoff, int2* __restrict__ e2)
{
    cg::grid_group grid = cg::this_grid();
    const int gtid = blockIdx.x * 1024 + threadIdx.x;

    // phase 0: zero counts + cursor
    if (gtid < NN) { counts[gtid] = 0; cursor[gtid] = 0; }
    grid.sync();

    // phase 1: histogram
    for (int e = gtid; e < NE; e += 262144) atomicAdd(&counts[rows[e]], 1);
    grid.sync();

    // phase 2: exclusive prefix sum (block 0 only)
    __shared__ int buf[1024];
    if (blockIdx.x == 0) {
        const int tid = threadIdx.x;
        const int base = tid * 10;                 // 1024*10 >= NN
        int loc[10]; int s = 0;
#pragma unroll
        for (int i = 0; i < 10; ++i) {
            int idx = base + i;
            int c = (idx < NN) ? counts[idx] : 0;
            loc[i] = s; s += c;
        }
        buf[tid] = s;
        __syncthreads();
        for (int off = 1; off < 1024; off <<= 1) {   // Hillis-Steele inclusive
            int v = (tid >= off) ? buf[tid - off] : 0;
            __syncthreads();
            buf[tid] += v;
            __syncthreads();
        }
        int pref = (tid == 0) ? 0 : buf[tid - 1];
#pragma unroll
        for (int i = 0; i < 10; ++i) {
            int idx = base + i;
            if (idx < NN) nodeoff[idx] = pref + loc[i];
        }
    }
    grid.sync();

    // phase 3: reorder into (row, col) pairs grouped by row
    for (int e = gtid; e < NE; e += 262144) {
        int r = rows[e];
        int p = nodeoff[r] + atomicAdd(&cursor[r], 1);
        e2[p] = make_int2(r, cols[e]);
    }
}

// non-cooperative fallback (no sort) if workspace is too small
__global__ void pack_edges(const int* __restrict__ rows, const int* __restrict__ cols,
                           int2* __restrict__ e2) {
    int e = blockIdx.x * 256 + threadIdx.x;
    if (e < NE) e2[e] = make_int2(rows[e], cols[e]);
}

// ---------- edge kernel ----------
// 1024 threads = 16 waves; 32 edges/wave (2 groups of 16); 512 edges/block.
__global__ __launch_bounds__(1024, 4) void edge_kernel(
    const short* __restrict__ featbf,
    const int2* __restrict__ e2,      // sorted (row, col) pairs
    const short* __restrict__ W12,    // swizzled: W1 [128][256] | W2 [128][128]
    const float* __restrict__ bm1,
    const float* __restrict__ bm2,
    float* __restrict__ agg)
{
    __shared__ __align__(16) short wlds[49152];   // 96 KB: W1 (64 KB) | W2 (32 KB)
    __shared__ float biasb[256];                  // bm1 | bm2
    const int tid = threadIdx.x;
    const int w = tid >> 6, l = tid & 63;
    const int q = l >> 4, l15 = l & 15;
    const int ebase = blockIdx.x * 512 + w * 32;

    // prefetch edge pairs (latency hides under weight staging)
    int2 ec[2];
    ec[0] = e2[ebase + l15];
    ec[1] = e2[ebase + 16 + l15];

    // stage weights (linear copy; source is pre-swizzled)
    {
        const short8* gs = (const short8*)W12;
        short8* ls = (short8*)wlds;
#pragma unroll
        for (int i = 0; i < 6; ++i) ls[i * 1024 + tid] = gs[i * 1024 + tid];
        if (tid < 128) biasb[tid] = bm1[tid];
        else if (tid < 256) biasb[tid] = bm2[tid - 128];
    }
    __syncthreads();

    int nodeA[2];
    const short* sp[2];
    const short* dp[2];
#pragma unroll
    for (int eg = 0; eg < 2; ++eg) {
        nodeA[eg] = ec[eg].x;
        sp[eg] = featbf + (size_t)ec[eg].x * 128;
        dp[eg] = featbf + (size_t)ec[eg].y * 128;
    }

    // ---- GEMM1 (swapped): hT[128][16] = Wm1T(A, LDS) x msg_inT(B, gathered) ----
    floatx4 acc1[8][2];
#pragma unroll
    for (int mt = 0; mt < 8; ++mt)
#pragma unroll
        for (int eg = 0; eg < 2; ++eg) acc1[mt][eg] = (floatx4)(0.f);

#pragma unroll
    for (int kk = 0; kk < 8; ++kk) {
        short8 bfr[2];
#pragma unroll
        for (int eg = 0; eg < 2; ++eg) {
            const short* p = (kk < 4) ? (sp[eg] + kk * 32 + q * 8)
                                      : (dp[eg] + (kk - 4) * 32 + q * 8);
            bfr[eg] = *(const short8*)p;
        }
#pragma unroll
        for (int mt = 0; mt < 8; ++mt) {
            const int m = mt * 16 + l15;
            const int idx = m * 256 + ((kk * 32 + q * 8) ^ ((m & 7) << 3));
            short8 afr = *(const short8*)(wlds + idx);
#pragma unroll
            for (int eg = 0; eg < 2; ++eg)
                acc1[mt][eg] = __builtin_amdgcn_mfma_f32_16x16x32_bf16(
                    afr, bfr[eg], acc1[mt][eg], 0, 0, 0);
        }
    }

    // W1 region (64 KB) dead from here; per-wave 4 KB h-buffers alias over it.
    __syncthreads();
    short (*hb)[16][128] = (short (*)[16][128])wlds;   // [16 waves][16 e][128]
    const int swzw = (l15 & 7) << 3;

    // ---- bias + sigmoid + transpose h via LDS; pull A-frags back to regs ----
    short8 hA[2][4];
#pragma unroll
    for (int eg = 0; eg < 2; ++eg) {
#pragma unroll
        for (int mt = 0; mt < 8; ++mt) {
            const int k0 = mt * 16 + q * 4;
            short4v hv;
            hv[0] = f2bf(sigmoidf_(acc1[mt][eg][0] + biasb[k0 + 0]));
            hv[1] = f2bf(sigmoidf_(acc1[mt][eg][1] + biasb[k0 + 1]));
            hv[2] = f2bf(sigmoidf_(acc1[mt][eg][2] + biasb[k0 + 2]));
            hv[3] = f2bf(sigmoidf_(acc1[mt][eg][3] + biasb[k0 + 3]));
            *(short4v*)&hb[w][l15][k0 ^ swzw] = hv;
        }
#pragma unroll
        for (int kk2 = 0; kk2 < 4; ++kk2)
            hA[eg][kk2] = *(const short8*)&hb[w][l15][(kk2 * 32 + q * 8) ^ swzw];
    }

    // ---- GEMM2 (non-swapped): msg[16 e][128 m] = h(A, regs) x Wm2(B, LDS) ----
    // each W2 fragment read once per wave, used for both edge-groups
    floatx4 acc2[8][2];
#pragma unroll
    for (int mt = 0; mt < 8; ++mt)
#pragma unroll
        for (int eg = 0; eg < 2; ++eg) acc2[mt][eg] = (floatx4)(0.f);
#pragma unroll
    for (int kk2 = 0; kk2 < 4; ++kk2) {
#pragma unroll
        for (int mt = 0; mt < 8; ++mt) {
            const int m = mt * 16 + l15;
            const int idx = 32768 + m * 128 + ((kk2 * 32 + q * 8) ^ ((m & 7) << 3));
            short8 wfr = *(const short8*)(wlds + idx);
#pragma unroll
            for (int eg = 0; eg < 2; ++eg)
                acc2[mt][eg] = __builtin_amdgcn_mfma_f32_16x16x32_bf16(
                    hA[eg][kk2], wfr, acc2[mt][eg], 0, 0, 0);
        }
    }

    // ---- softsign + in-register 16-edge reduction + coalesced scatter ----
#pragma unroll
    for (int eg = 0; eg < 2; ++eg) {
        const int n0 = __shfl(nodeA[eg], 0);
        const bool uni = (bool)__all(nodeA[eg] == n0);
        if (uni) {
#pragma unroll
            for (int mt = 0; mt < 8; ++mt) {
                const float b = biasb[128 + mt * 16 + l15];
                float s = softsignf_(acc2[mt][eg][0] + b) + softsignf_(acc2[mt][eg][1] + b)
                        + softsignf_(acc2[mt][eg][2] + b) + softsignf_(acc2[mt][eg][3] + b);
                s += __shfl_xor(s, 16);
                s += __shfl_xor(s, 32);
                if (q == 0) atomicAdd(&agg[(size_t)n0 * 128 + mt * 16 + l15], s);
            }
        } else {
            int nd[4];
#pragma unroll
            for (int r = 0; r < 4; ++r) nd[r] = __shfl(nodeA[eg], q * 4 + r);
#pragma unroll
            for (int mt = 0; mt < 8; ++mt) {
                const float b = biasb[128 + mt * 16 + l15];
                float run = 0.f;
#pragma unroll
                for (int r = 0; r < 4; ++r) {
                    run += softsignf_(acc2[mt][eg][r] + b);
                    if (r == 3 || nd[r + 1] != nd[r]) {
                        atomicAdd(&agg[(size_t)nd[r] * 128 + mt * 16 + l15], run);
                        run = 0.f;
                    }
                }
            }
        }
    }
}

// ---------- node kernel (unchanged, R1-verified) ----------
__global__ __launch_bounds__(256) void node_kernel(
    const float* __restrict__ feat,
    const float* __restrict__ agg,
    const float* __restrict__ temb,
    const short* __restrict__ Wf1T,
    const float* __restrict__ bf1v,
    const short* __restrict__ Wf2T,
    const float* __restrict__ bf2v,
    float* __restrict__ out)
{
    __shared__ __align__(16) short gbuf[4][16][128];
    const int tid = threadIdx.x;
    const int w = tid >> 6, l = tid & 63;
    const int l15 = l & 15, q = l >> 4;
    const int nbase = blockIdx.x * 64 + w * 16;
    if (nbase >= NN) return;

    const int nA = nbase + l15;
    const float* p0 = feat + (size_t)nA * 128 + q * 8;
    const float* p1 = agg + (size_t)nA * 128 + q * 8;
    const float* p2 = temb + (size_t)nA * 128 + q * 8;

    floatx4 acc[8];
#pragma unroll
    for (int i = 0; i < 8; ++i) acc[i] = (floatx4)(0.f);

#pragma unroll
    for (int kk = 0; kk < 12; ++kk) {                   // K = 384 = 12 x 32
        const float* ap = (kk < 4) ? (p0 + kk * 32)
                        : (kk < 8) ? (p1 + (kk - 4) * 32)
                                   : (p2 + (kk - 8) * 32);
        const float4 a0 = *(const float4*)(ap);
        const float4 a1 = *(const float4*)(ap + 4);
        short8 af;
        af[0] = f2bf(sigmoidf_(a0.x)); af[1] = f2bf(sigmoidf_(a0.y));
        af[2] = f2bf(sigmoidf_(a0.z)); af[3] = f2bf(sigmoidf_(a0.w));
        af[4] = f2bf(sigmoidf_(a1.x)); af[5] = f2bf(sigmoidf_(a1.y));
        af[6] = f2bf(sigmoidf_(a1.z)); af[7] = f2bf(sigmoidf_(a1.w));
        const int krow = kk * 32 + q * 8;
#pragma unroll
        for (int ct = 0; ct < 8; ++ct) {
            const int col = ct * 16 + l15;
            short8 bf = *(const short8*)(Wf1T + col * 384 + krow);
            acc[ct] = __builtin_amdgcn_mfma_f32_16x16x32_bf16(af, bf, acc[ct], 0, 0, 0);
        }
    }

#pragma unroll
    for (int ct = 0; ct < 8; ++ct) {
        const int col = ct * 16 + l15;
        const float b = bf1v[col];
#pragma unroll
        for (int r = 0; r < 4; ++r) {
            gbuf[w][q * 4 + r][col] = f2bf(sigmoidf_(acc[ct][r] + b));
        }
    }

    floatx4 acc2[8];
#pragma unroll
    for (int i = 0; i < 8; ++i) acc2[i] = (floatx4)(0.f);
#pragma unroll
    for (int kk = 0; kk < 4; ++kk) {
        const int krow = kk * 32 + q * 8;
        short8 af = *(const short8*)(&gbuf[w][l15][krow]);
#pragma unroll
        for (int ct = 0; ct < 8; ++ct) {
            const int col = ct * 16 + l15;
            short8 bf = *(const short8*)(Wf2T + col * 128 + krow);
            acc2[ct] = __builtin_amdgcn_mfma_f32_16x16x32_bf16(af, bf, acc2[ct], 0, 0, 0);
        }
    }

#pragma unroll
    for (int ct = 0; ct < 8; ++ct) {
        const int col = ct * 16 + l15;
        const float b = bf2v[col];
#pragma unroll
        for (int r = 0; r < 4; ++r) {
            const int node = nbase + q * 4 + r;
            out[(size_t)node * 128 + col] = softsignf_(acc2[ct][r] + b);
        }
    }
}

extern "C" void kernel_launch(void* const* d_in, const int* in_sizes, int n_in,
                              void* d_out, int out_size, void* d_ws, size_t ws_size,
                              hipStream_t stream)
{
    const float* feat = (const float*)d_in[0];
    const int* rows = (const int*)d_in[1];
    const int* cols = (const int*)d_in[2];
    const float* temb = (const float*)d_in[3];
    const float* Wm1 = (const float*)d_in[4];
    const float* bm1 = (const float*)d_in[5];
    const float* Wm2 = (const float*)d_in[6];
    const float* bm2 = (const float*)d_in[7];
    const float* Wf1 = (const float*)d_in[8];
    const float* bf1 = (const float*)d_in[9];
    const float* Wf2 = (const float*)d_in[10];
    const float* bf2 = (const float*)d_in[11];
    float* out = (float*)d_out;

    // Workspace layout (16B-aligned):
    //   agg    f32  [10000][128]      5,120,000 B   @ 0
    //   fbf    bf16 [10000][128]      2,560,000 B   @ 5,120,000
    //   W12    bf16 swz W1|W2            98,304 B   @ 7,680,000
    //   Wf1T   bf16 [128][384]           98,304 B   @ 7,778,304
    //   Wf2T   bf16 [128][128]           32,768 B   @ 7,876,608
    //   e2     int2 [NE]              5,120,000 B   @ 7,909,376
    //   counts i32  [NN]                 40,000 B   @ 13,029,376
    //   cursor i32  [NN]                 40,000 B   @ 13,069,376
    //   nodeoff i32 [NN]                 40,000 B   @ 13,109,376
    char* ws = (char*)d_ws;
    float* agg   = (float*)ws;
    short* fbf   = (short*)(ws + 5120000);
    short* W12   = (short*)(ws + 7680000);
    short* Wf1T  = (short*)(ws + 7778304);
    short* Wf2T  = (short*)(ws + 7876608);
    int2* e2     = (int2*)(ws + 7909376);
    int* counts  = (int*)(ws + 13029376);
    int* cursor  = (int*)(ws + 13069376);
    int* nodeoff = (int*)(ws + 13109376);
    const size_t NEEDED = 13149376;

    prep_all<<<2948, 256, 0, stream>>>(feat, Wm1, Wm2, Wf1, Wf2,
                                       agg, fbf, W12, Wf1T, Wf2T);

    if (ws_size >= NEEDED) {
        void* args[] = {(void*)&rows, (void*)&cols, (void*)&counts,
                        (void*)&cursor, (void*)&nodeoff, (void*)&e2};
        hipLaunchCooperativeKernel((void*)sort_fused, dim3(256), dim3(1024),
                                   args, 0, stream);
    } else {
        pack_edges<<<(NE + 255) / 256, 256, 0, stream>>>(rows, cols, e2);
    }

    edge_kernel<<<NE / 512, 1024, 0, stream>>>(fbf, e2, W12, bm1, bm2, agg);
    node_kernel<<<(NN + 63) / 64, 256, 0, stream>>>(feat, agg, temb, Wf1T, bf1, Wf2T, bf2, out);
}

// Round 9
// 244.194 us; speedup vs baseline: 1.3006x; 1.3006x over previous
//
#include <hip/hip_runtime.h>
#include <hip/hip_bf16.h>

// Graph message-passing layer, bf16 MFMA implementation, v9.
// = v8 with the h-pack reverted to the verified f2bf path (v_cvt_pk_bf16_f32
// inline asm mis-packs here — R2 and R8 both failed with it; all passing
// rounds use f2bf). Non-cooperative sort chain; v7 edge kernel structure.
// N=10000 nodes, E=640000 edges, F=M=O=128.

#define NN 10000
#define NE 640000

typedef __attribute__((ext_vector_type(8))) short short8;
typedef __attribute__((ext_vector_type(4))) short short4v;
typedef __attribute__((ext_vector_type(4))) float floatx4;

__device__ __forceinline__ short f2bf(float f) {
    union { float f; unsigned u; } v; v.f = f;
    unsigned r = v.u + 0x7fffu + ((v.u >> 16) & 1u);   // RNE, NaN-free inputs
    return (short)(r >> 16);
}

__device__ __forceinline__ float sigmoidf_(float x) {
    return __builtin_amdgcn_rcpf(1.f + __expf(-x));
}
__device__ __forceinline__ float softsignf_(float x) {
    return x * __builtin_amdgcn_rcpf(1.f + fabsf(x));
}

// ---------- fused prep kernel ----------
// partitions: [0,1250) agg zero | [1250,2500) feat->bf16 | [2500,2628) Wm1 swz
// | [2628,2692) Wm2 swz | [2692,2884) Wf1 T | [2884,2948) Wf2 T | [2948,5448) hist
__global__ __launch_bounds__(256) void prep_all(
    const float* __restrict__ feat, const int* __restrict__ rows,
    const float* __restrict__ Wm1, const float* __restrict__ Wm2,
    const float* __restrict__ Wf1, const float* __restrict__ Wf2,
    float* __restrict__ agg, short* __restrict__ fbf, short* __restrict__ W12,
    short* __restrict__ Wf1T, short* __restrict__ Wf2T, int* __restrict__ counts)
{
    const int bid = blockIdx.x, tid = threadIdx.x;
    if (bid < 1250) {                       // zero agg: 1,280,000 f32 = 320,000 f4
        int i = bid * 256 + tid;
        ((float4*)agg)[i] = make_float4(0.f, 0.f, 0.f, 0.f);
    } else if (bid < 2500) {                // features f32 -> bf16, 4/thread
        int i = (bid - 1250) * 256 + tid;   // n4 = 320000, exact
        float4 v = ((const float4*)feat)[i];
        short4v o;
        o[0] = f2bf(v.x); o[1] = f2bf(v.y); o[2] = f2bf(v.z); o[3] = f2bf(v.w);
        ((short4v*)fbf)[i] = o;
    } else if (bid < 2628) {                // Wm1 [256][128] -> swz [128][256]
        int i = (bid - 2500) * 256 + tid;   // 32768, exact
        int m = i >> 8, k = i & 255;
        W12[m * 256 + (k ^ ((m & 7) << 3))] = f2bf(Wm1[k * 128 + m]);
    } else if (bid < 2692) {                // Wm2 [128][128] -> swz
        int i = (bid - 2628) * 256 + tid;   // 16384, exact
        int m = i >> 7, k = i & 127;
        W12[32768 + m * 128 + (k ^ ((m & 7) << 3))] = f2bf(Wm2[k * 128 + m]);
    } else if (bid < 2884) {                // Wf1 [384][128] -> T [128][384]
        int i = (bid - 2692) * 256 + tid;   // 49152, exact
        int c = i / 384, k = i - c * 384;
        Wf1T[i] = f2bf(Wf1[k * 128 + c]);
    } else if (bid < 2948) {                // Wf2 [128][128] -> T
        int i = (bid - 2884) * 256 + tid;   // 16384, exact
        int c = i >> 7, k = i & 127;
        Wf2T[i] = f2bf(Wf2[k * 128 + c]);
    } else {                                // histogram of rows
        int e = (bid - 2948) * 256 + tid;   // 640000, exact
        atomicAdd(&counts[rows[e]], 1);
    }
}

// exclusive prefix sum over counts[NN], single 1024-thread block
__global__ __launch_bounds__(1024) void scan_kernel(const int* __restrict__ counts,
                                                    int* __restrict__ nodeoff) {
    __shared__ int buf[1024];
    const int tid = threadIdx.x;
    const int base = tid * 10;                 // 1024*10 >= NN
    int loc[10]; int s = 0;
#pragma unroll
    for (int i = 0; i < 10; ++i) {
        int idx = base + i;
        int c = (idx < NN) ? counts[idx] : 0;
        loc[i] = s; s += c;
    }
    buf[tid] = s;
    __syncthreads();
    for (int off = 1; off < 1024; off <<= 1) {   // Hillis-Steele inclusive
        int v = (tid >= off) ? buf[tid - off] : 0;
        __syncthreads();
        buf[tid] += v;
        __syncthreads();
    }
    int pref = (tid == 0) ? 0 : buf[tid - 1];
#pragma unroll
    for (int i = 0; i < 10; ++i) {
        int idx = base + i;
        if (idx < NN) nodeoff[idx] = pref + loc[i];
    }
}

// reorder; nodeoff doubles as the cursor (destroyed here, dead afterward)
__global__ void reorder_kernel(const int* __restrict__ rows, const int* __restrict__ cols,
                               int* __restrict__ nodeoff, int2* __restrict__ e2) {
    int e = blockIdx.x * 256 + threadIdx.x;
    if (e >= NE) return;
    int r = rows[e];
    int p = atomicAdd(&nodeoff[r], 1);
    e2[p] = make_int2(r, cols[e]);
}

// non-sorted fallback if workspace is too small
__global__ void pack_edges(const int* __restrict__ rows, const int* __restrict__ cols,
                           int2* __restrict__ e2) {
    int e = blockIdx.x * 256 + threadIdx.x;
    if (e < NE) e2[e] = make_int2(rows[e], cols[e]);
}

// ---------- edge kernel ----------
// 1024 threads = 16 waves; 32 edges/wave (2 groups of 16); 512 edges/block.
__global__ __launch_bounds__(1024, 4) void edge_kernel(
    const short* __restrict__ featbf,
    const int2* __restrict__ e2,      // sorted (row, col) pairs
    const short* __restrict__ W12,    // swizzled: W1 [128][256] | W2 [128][128]
    const float* __restrict__ bm1,
    const float* __restrict__ bm2,
    float* __restrict__ agg)
{
    __shared__ __align__(16) short wlds[49152];   // 96 KB: W1 (64 KB) | W2 (32 KB)
    __shared__ float biasb[256];                  // bm1 | bm2
    const int tid = threadIdx.x;
    const int w = tid >> 6, l = tid & 63;
    const int q = l >> 4, l15 = l & 15;
    const int ebase = blockIdx.x * 512 + w * 32;

    // prefetch edge pairs (latency hides under weight staging)
    int2 ec[2];
    ec[0] = e2[ebase + l15];
    ec[1] = e2[ebase + 16 + l15];

    // stage weights (linear copy; source is pre-swizzled)
    {
        const short8* gs = (const short8*)W12;
        short8* ls = (short8*)wlds;
#pragma unroll
        for (int i = 0; i < 6; ++i) ls[i * 1024 + tid] = gs[i * 1024 + tid];
        if (tid < 128) biasb[tid] = bm1[tid];
        else if (tid < 256) biasb[tid] = bm2[tid - 128];
    }
    __syncthreads();

    int nodeA[2];
    const short* sp[2];
    const short* dp[2];
#pragma unroll
    for (int eg = 0; eg < 2; ++eg) {
        nodeA[eg] = ec[eg].x;
        sp[eg] = featbf + (size_t)ec[eg].x * 128;
        dp[eg] = featbf + (size_t)ec[eg].y * 128;
    }

    // ---- GEMM1 (swapped): hT[128][16] = Wm1T(A, LDS) x msg_inT(B, gathered) ----
    floatx4 acc1[8][2];
#pragma unroll
    for (int mt = 0; mt < 8; ++mt)
#pragma unroll
        for (int eg = 0; eg < 2; ++eg) acc1[mt][eg] = (floatx4)(0.f);

#pragma unroll
    for (int kk = 0; kk < 8; ++kk) {
        short8 bfr[2];
#pragma unroll
        for (int eg = 0; eg < 2; ++eg) {
            const short* p = (kk < 4) ? (sp[eg] + kk * 32 + q * 8)
                                      : (dp[eg] + (kk - 4) * 32 + q * 8);
            bfr[eg] = *(const short8*)p;
        }
#pragma unroll
        for (int mt = 0; mt < 8; ++mt) {
            const int m = mt * 16 + l15;
            const int idx = m * 256 + ((kk * 32 + q * 8) ^ ((m & 7) << 3));
            short8 afr = *(const short8*)(wlds + idx);
#pragma unroll
            for (int eg = 0; eg < 2; ++eg)
                acc1[mt][eg] = __builtin_amdgcn_mfma_f32_16x16x32_bf16(
                    afr, bfr[eg], acc1[mt][eg], 0, 0, 0);
        }
    }

    // W1 region (64 KB) dead from here; per-wave 4 KB h-buffers alias over it.
    __syncthreads();
    short (*hb)[16][128] = (short (*)[16][128])wlds;   // [16 waves][16 e][128]
    const int swzw = (l15 & 7) << 3;

    // ---- bias + sigmoid + transpose h via LDS; pull A-frags back to regs ----
    short8 hA[2][4];
#pragma unroll
    for (int eg = 0; eg < 2; ++eg) {
#pragma unroll
        for (int mt = 0; mt < 8; ++mt) {
            const int k0 = mt * 16 + q * 4;
            short4v hv;
            hv[0] = f2bf(sigmoidf_(acc1[mt][eg][0] + biasb[k0 + 0]));
            hv[1] = f2bf(sigmoidf_(acc1[mt][eg][1] + biasb[k0 + 1]));
            hv[2] = f2bf(sigmoidf_(acc1[mt][eg][2] + biasb[k0 + 2]));
            hv[3] = f2bf(sigmoidf_(acc1[mt][eg][3] + biasb[k0 + 3]));
            *(short4v*)&hb[w][l15][k0 ^ swzw] = hv;
        }
#pragma unroll
        for (int kk2 = 0; kk2 < 4; ++kk2)
            hA[eg][kk2] = *(const short8*)&hb[w][l15][(kk2 * 32 + q * 8) ^ swzw];
    }

    // ---- GEMM2 (non-swapped): msg[16 e][128 m] = h(A, regs) x Wm2(B, LDS) ----
    // each W2 fragment read once per wave, used for both edge-groups
    floatx4 acc2[8][2];
#pragma unroll
    for (int mt = 0; mt < 8; ++mt)
#pragma unroll
        for (int eg = 0; eg < 2; ++eg) acc2[mt][eg] = (floatx4)(0.f);
#pragma unroll
    for (int kk2 = 0; kk2 < 4; ++kk2) {
#pragma unroll
        for (int mt = 0; mt < 8; ++mt) {
            const int m = mt * 16 + l15;
            const int idx = 32768 + m * 128 + ((kk2 * 32 + q * 8) ^ ((m & 7) << 3));
            short8 wfr = *(const short8*)(wlds + idx);
#pragma unroll
            for (int eg = 0; eg < 2; ++eg)
                acc2[mt][eg] = __builtin_amdgcn_mfma_f32_16x16x32_bf16(
                    hA[eg][kk2], wfr, acc2[mt][eg], 0, 0, 0);
        }
    }

    // ---- softsign + in-register 16-edge reduction + coalesced scatter ----
#pragma unroll
    for (int eg = 0; eg < 2; ++eg) {
        const int n0 = __shfl(nodeA[eg], 0);
        const bool uni = (bool)__all(nodeA[eg] == n0);
        if (uni) {
#pragma unroll
            for (int mt = 0; mt < 8; ++mt) {
                const float b = biasb[128 + mt * 16 + l15];
                float s = softsignf_(acc2[mt][eg][0] + b) + softsignf_(acc2[mt][eg][1] + b)
                        + softsignf_(acc2[mt][eg][2] + b) + softsignf_(acc2[mt][eg][3] + b);
                s += __shfl_xor(s, 16);
                s += __shfl_xor(s, 32);
                if (q == 0) atomicAdd(&agg[(size_t)n0 * 128 + mt * 16 + l15], s);
            }
        } else {
            int nd[4];
#pragma unroll
            for (int r = 0; r < 4; ++r) nd[r] = __shfl(nodeA[eg], q * 4 + r);
#pragma unroll
            for (int mt = 0; mt < 8; ++mt) {
                const float b = biasb[128 + mt * 16 + l15];
                float run = 0.f;
#pragma unroll
                for (int r = 0; r < 4; ++r) {
                    run += softsignf_(acc2[mt][eg][r] + b);
                    if (r == 3 || nd[r + 1] != nd[r]) {
                        atomicAdd(&agg[(size_t)nd[r] * 128 + mt * 16 + l15], run);
                        run = 0.f;
                    }
                }
            }
        }
    }
}

// ---------- node kernel (unchanged, R1-verified) ----------
__global__ __launch_bounds__(256) void node_kernel(
    const float* __restrict__ feat,
    const float* __restrict__ agg,
    const float* __restrict__ temb,
    const short* __restrict__ Wf1T,
    const float* __restrict__ bf1v,
    const short* __restrict__ Wf2T,
    const float* __restrict__ bf2v,
    float* __restrict__ out)
{
    __shared__ __align__(16) short gbuf[4][16][128];
    const int tid = threadIdx.x;
    const int w = tid >> 6, l = tid & 63;
    const int l15 = l & 15, q = l >> 4;
    const int nbase = blockIdx.x * 64 + w * 16;
    if (nbase >= NN) return;

    const int nA = nbase + l15;
    const float* p0 = feat + (size_t)nA * 128 + q * 8;
    const float* p1 = agg + (size_t)nA * 128 + q * 8;
    const float* p2 = temb + (size_t)nA * 128 + q * 8;

    floatx4 acc[8];
#pragma unroll
    for (int i = 0; i < 8; ++i) acc[i] = (floatx4)(0.f);

#pragma unroll
    for (int kk = 0; kk < 12; ++kk) {                   // K = 384 = 12 x 32
        const float* ap = (kk < 4) ? (p0 + kk * 32)
                        : (kk < 8) ? (p1 + (kk - 4) * 32)
                                   : (p2 + (kk - 8) * 32);
        const float4 a0 = *(const float4*)(ap);
        const float4 a1 = *(const float4*)(ap + 4);
        short8 af;
        af[0] = f2bf(sigmoidf_(a0.x)); af[1] = f2bf(sigmoidf_(a0.y));
        af[2] = f2bf(sigmoidf_(a0.z)); af[3] = f2bf(sigmoidf_(a0.w));
        af[4] = f2bf(sigmoidf_(a1.x)); af[5] = f2bf(sigmoidf_(a1.y));
        af[6] = f2bf(sigmoidf_(a1.z)); af[7] = f2bf(sigmoidf_(a1.w));
        const int krow = kk * 32 + q * 8;
#pragma unroll
        for (int ct = 0; ct < 8; ++ct) {
            const int col = ct * 16 + l15;
            short8 bf = *(const short8*)(Wf1T + col * 384 + krow);
            acc[ct] = __builtin_amdgcn_mfma_f32_16x16x32_bf16(af, bf, acc[ct], 0, 0, 0);
        }
    }

#pragma unroll
    for (int ct = 0; ct < 8; ++ct) {
        const int col = ct * 16 + l15;
        const float b = bf1v[col];
#pragma unroll
        for (int r = 0; r < 4; ++r) {
            gbuf[w][q * 4 + r][col] = f2bf(sigmoidf_(acc[ct][r] + b));
        }
    }

    floatx4 acc2[8];
#pragma unroll
    for (int i = 0; i < 8; ++i) acc2[i] = (floatx4)(0.f);
#pragma unroll
    for (int kk = 0; kk < 4; ++kk) {
        const int krow = kk * 32 + q * 8;
        short8 af = *(const short8*)(&gbuf[w][l15][krow]);
#pragma unroll
        for (int ct = 0; ct < 8; ++ct) {
            const int col = ct * 16 + l15;
            short8 bf = *(const short8*)(Wf2T + col * 128 + krow);
            acc2[ct] = __builtin_amdgcn_mfma_f32_16x16x32_bf16(af, bf, acc2[ct], 0, 0, 0);
        }
    }

#pragma unroll
    for (int ct = 0; ct < 8; ++ct) {
        const int col = ct * 16 + l15;
        const float b = bf2v[col];
#pragma unroll
        for (int r = 0; r < 4; ++r) {
            const int node = nbase + q * 4 + r;
            out[(size_t)node * 128 + col] = softsignf_(acc2[ct][r] + b);
        }
    }
}

extern "C" void kernel_launch(void* const* d_in, const int* in_sizes, int n_in,
                              void* d_out, int out_size, void* d_ws, size_t ws_size,
                              hipStream_t stream)
{
    const float* feat = (const float*)d_in[0];
    const int* rows = (const int*)d_in[1];
    const int* cols = (const int*)d_in[2];
    const float* temb = (const float*)d_in[3];
    const float* Wm1 = (const float*)d_in[4];
    const float* bm1 = (const float*)d_in[5];
    const float* Wm2 = (const float*)d_in[6];
    const float* bm2 = (const float*)d_in[7];
    const float* Wf1 = (const float*)d_in[8];
    const float* bf1 = (const float*)d_in[9];
    const float* Wf2 = (const float*)d_in[10];
    const float* bf2 = (const float*)d_in[11];
    float* out = (float*)d_out;

    // Workspace layout (16B-aligned):
    //   agg    f32  [10000][128]      5,120,000 B   @ 0
    //   fbf    bf16 [10000][128]      2,560,000 B   @ 5,120,000
    //   W12    bf16 swz W1|W2            98,304 B   @ 7,680,000
    //   Wf1T   bf16 [128][384]           98,304 B   @ 7,778,304
    //   Wf2T   bf16 [128][128]           32,768 B   @ 7,876,608
    //   e2     int2 [NE]              5,120,000 B   @ 7,909,376
    //   counts i32  [NN]                 40,000 B   @ 13,029,376
    //   nodeoff i32 [NN]                 40,000 B   @ 13,069,376
    char* ws = (char*)d_ws;
    float* agg   = (float*)ws;
    short* fbf   = (short*)(ws + 5120000);
    short* W12   = (short*)(ws + 7680000);
    short* Wf1T  = (short*)(ws + 7778304);
    short* Wf2T  = (short*)(ws + 7876608);
    int2* e2     = (int2*)(ws + 7909376);
    int* counts  = (int*)(ws + 13029376);
    int* nodeoff = (int*)(ws + 13069376);
    const size_t NEEDED = 13109376;

    if (ws_size >= NEEDED) {
        hipMemsetAsync(counts, 0, NN * sizeof(int), stream);
        prep_all<<<5448, 256, 0, stream>>>(feat, rows, Wm1, Wm2, Wf1, Wf2,
                                           agg, fbf, W12, Wf1T, Wf2T, counts);
        scan_kernel<<<1, 1024, 0, stream>>>(counts, nodeoff);
        reorder_kernel<<<(NE + 255) / 256, 256, 0, stream>>>(rows, cols, nodeoff, e2);
    } else {
        prep_all<<<5448, 256, 0, stream>>>(feat, rows, Wm1, Wm2, Wf1, Wf2,
                                           agg, fbf, W12, Wf1T, Wf2T, counts);
        pack_edges<<<(NE + 255) / 256, 256, 0, stream>>>(rows, cols, e2);
    }

    edge_kernel<<<NE / 512, 1024, 0, stream>>>(fbf, e2, W12, bm1, bm2, agg);
    node_kernel<<<(NN + 63) / 64, 256, 0, stream>>>(feat, agg, temb, Wf1T, bf1, Wf2T, bf2, out);
}

// Round 10
// 229.769 us; speedup vs baseline: 1.3823x; 1.0628x over previous
//
#include <hip/hip_runtime.h>
#include <hip/hip_bf16.h>

// Graph message-passing layer, bf16 MFMA implementation, v10.
// Structural change vs v9: GEMM1 factored through nodes.
//   U = feat*W1a + bm1, V = feat*W1b   (per-node, one small GEMM kernel)
//   h[e] = sigmoid(U[rows[e]] + V[cols[e]])  (computed in registers, no LDS)
//   msg[e] = softsign(h[e]*W2 + bm2)         (MFMA, W2 in 32KB LDS)
// Edge kernel: no W1 staging, no h transpose, LDS 99KB->33KB.
// agg aliases d_out (node n reads agg row n before writing out row n).
// Packed edge list: (r<<14)|c in one int (both < 16384).
// N=10000 nodes, E=640000 edges, F=M=O=128.

#define NN 10000
#define NE 640000

typedef __attribute__((ext_vector_type(8))) short short8;
typedef __attribute__((ext_vector_type(4))) short short4v;
typedef __attribute__((ext_vector_type(4))) float floatx4;

__device__ __forceinline__ short f2bf(float f) {
    union { float f; unsigned u; } v; v.f = f;
    unsigned r = v.u + 0x7fffu + ((v.u >> 16) & 1u);   // RNE, NaN-free inputs
    return (short)(r >> 16);
}

__device__ __forceinline__ float sigmoidf_(float x) {
    return __builtin_amdgcn_rcpf(1.f + __expf(-x));
}
__device__ __forceinline__ float softsignf_(float x) {
    return x * __builtin_amdgcn_rcpf(1.f + fabsf(x));
}

// ---------- fused prep kernel ----------
// partitions: [0,1250) agg(=d_out) zero | [1250,3750) hist | [3750,3878) WuvT
// | [3878,3942) W2 swz | [3942,4134) Wf1T | [4134,4198) Wf2T
__global__ __launch_bounds__(256) void prep_all(
    const int* __restrict__ rows,
    const float* __restrict__ Wm1, const float* __restrict__ Wm2,
    const float* __restrict__ Wf1, const float* __restrict__ Wf2,
    float* __restrict__ agg, short* __restrict__ WuvT, short* __restrict__ W2s,
    short* __restrict__ Wf1T, short* __restrict__ Wf2T, int* __restrict__ counts)
{
    const int bid = blockIdx.x, tid = threadIdx.x;
    if (bid < 1250) {                       // zero agg: 1,280,000 f32 = 320,000 f4
        int i = bid * 256 + tid;
        ((float4*)agg)[i] = make_float4(0.f, 0.f, 0.f, 0.f);
    } else if (bid < 3750) {                // histogram of rows
        int e = (bid - 1250) * 256 + tid;   // 640000, exact
        atomicAdd(&counts[rows[e]], 1);
    } else if (bid < 3878) {                // WuvT[256][128]: c<128 -> W1a^T, else W1b^T
        int i = (bid - 3750) * 256 + tid;   // 32768, exact
        int c = i >> 7, k = i & 127;
        WuvT[i] = f2bf(Wm1[(k + ((c >> 7) << 7)) * 128 + (c & 127)]);
    } else if (bid < 3942) {                // Wm2 [128][128] -> swz [m][k^((m&7)<<3)]
        int i = (bid - 3878) * 256 + tid;   // 16384, exact
        int m = i >> 7, k = i & 127;
        W2s[m * 128 + (k ^ ((m & 7) << 3))] = f2bf(Wm2[k * 128 + m]);
    } else if (bid < 4134) {                // Wf1 [384][128] -> T [128][384]
        int i = (bid - 3942) * 256 + tid;   // 49152, exact
        int c = i / 384, k = i - c * 384;
        Wf1T[i] = f2bf(Wf1[k * 128 + c]);
    } else {                                // Wf2 [128][128] -> T
        int i = (bid - 4134) * 256 + tid;   // 16384, exact
        int c = i >> 7, k = i & 127;
        Wf2T[i] = f2bf(Wf2[k * 128 + c]);
    }
}

// ---------- U|V kernel: [10000,128] x [128,256] ----------
// U[n][m] = sum_k feat[n][k]*Wm1[k][m] + bm1[m]; V[n][m] = sum_k feat[n][k]*Wm1[128+k][m]
__global__ __launch_bounds__(256) void uv_kernel(
    const float* __restrict__ feat,
    const short* __restrict__ WuvT,   // [256 c][128 k] bf16
    const float* __restrict__ bm1,
    float* __restrict__ U, float* __restrict__ V)
{
    const int tid = threadIdx.x;
    const int w = tid >> 6, l = tid & 63;
    const int l15 = l & 15, q = l >> 4;
    const int nbase = blockIdx.x * 64 + w * 16;
    if (nbase >= NN) return;

    const int nA = nbase + l15;
    const float* p0 = feat + (size_t)nA * 128;

    floatx4 acc[16];
#pragma unroll
    for (int i = 0; i < 16; ++i) acc[i] = (floatx4)(0.f);

#pragma unroll
    for (int kk = 0; kk < 4; ++kk) {                    // K = 128
        const int krow = kk * 32 + q * 8;
        const float4 a0 = *(const float4*)(p0 + krow);
        const float4 a1 = *(const float4*)(p0 + krow + 4);
        short8 af;
        af[0] = f2bf(a0.x); af[1] = f2bf(a0.y); af[2] = f2bf(a0.z); af[3] = f2bf(a0.w);
        af[4] = f2bf(a1.x); af[5] = f2bf(a1.y); af[6] = f2bf(a1.z); af[7] = f2bf(a1.w);
#pragma unroll
        for (int ct = 0; ct < 16; ++ct) {
            const int c = ct * 16 + l15;
            short8 bf = *(const short8*)(WuvT + c * 128 + krow);
            acc[ct] = __builtin_amdgcn_mfma_f32_16x16x32_bf16(af, bf, acc[ct], 0, 0, 0);
        }
    }

#pragma unroll
    for (int ct = 0; ct < 8; ++ct) {
        const int c = ct * 16 + l15;
        const float b = bm1[c];
#pragma unroll
        for (int r = 0; r < 4; ++r)
            U[(size_t)(nbase + q * 4 + r) * 128 + c] = acc[ct][r] + b;
    }
#pragma unroll
    for (int ct = 8; ct < 16; ++ct) {
        const int c = ct * 16 + l15 - 128;
#pragma unroll
        for (int r = 0; r < 4; ++r)
            V[(size_t)(nbase + q * 4 + r) * 128 + c] = acc[ct][r];
    }
}

// exclusive prefix sum over counts[NN], single 1024-thread block
__global__ __launch_bounds__(1024) void scan_kernel(const int* __restrict__ counts,
                                                    int* __restrict__ nodeoff) {
    __shared__ int buf[1024];
    const int tid = threadIdx.x;
    const int base = tid * 10;                 // 1024*10 >= NN
    int loc[10]; int s = 0;
#pragma unroll
    for (int i = 0; i < 10; ++i) {
        int idx = base + i;
        int c = (idx < NN) ? counts[idx] : 0;
        loc[i] = s; s += c;
    }
    buf[tid] = s;
    __syncthreads();
    for (int off = 1; off < 1024; off <<= 1) {   // Hillis-Steele inclusive
        int v = (tid >= off) ? buf[tid - off] : 0;
        __syncthreads();
        buf[tid] += v;
        __syncthreads();
    }
    int pref = (tid == 0) ? 0 : buf[tid - 1];
#pragma unroll
    for (int i = 0; i < 10; ++i) {
        int idx = base + i;
        if (idx < NN) nodeoff[idx] = pref + loc[i];
    }
}

// reorder; nodeoff doubles as the cursor (destroyed here, dead afterward)
__global__ void reorder_kernel(const int* __restrict__ rows, const int* __restrict__ cols,
                               int* __restrict__ nodeoff, int* __restrict__ e1) {
    int e = blockIdx.x * 256 + threadIdx.x;
    if (e >= NE) return;
    int r = rows[e];
    int p = atomicAdd(&nodeoff[r], 1);
    e1[p] = (r << 14) | cols[e];
}

// non-sorted fallback if workspace is too small
__global__ void pack_edges(const int* __restrict__ rows, const int* __restrict__ cols,
                           int* __restrict__ e1) {
    int e = blockIdx.x * 256 + threadIdx.x;
    if (e < NE) e1[e] = (rows[e] << 14) | cols[e];
}

// ---------- edge kernel ----------
// 1024 threads = 16 waves; 32 edges/wave (2 serial groups of 16); 512 edges/block.
__global__ __launch_bounds__(1024, 4) void edge_kernel(
    const float* __restrict__ U,
    const float* __restrict__ V,
    const int* __restrict__ e1,       // sorted packed (r<<14)|c
    const short* __restrict__ W2s,    // swizzled [128][128]
    const float* __restrict__ bm2,
    float* agg)
{
    __shared__ __align__(16) short wlds[16384];   // 32 KB: W2
    __shared__ float biasb[128];                  // bm2
    const int tid = threadIdx.x;
    const int w = tid >> 6, l = tid & 63;
    const int q = l >> 4, l15 = l & 15;
    const int ebase = blockIdx.x * 512 + w * 32;

    // prefetch packed edges (hides under W2 staging)
    int ep[2];
    ep[0] = e1[ebase + l15];
    ep[1] = e1[ebase + 16 + l15];

    // stage W2 (linear copy; source is pre-swizzled)
    {
        const short8* gs = (const short8*)W2s;
        short8* ls = (short8*)wlds;
        ls[tid] = gs[tid];
        ls[1024 + tid] = gs[1024 + tid];
        if (tid < 128) biasb[tid] = bm2[tid];
    }
    __syncthreads();

#pragma unroll
    for (int eg = 0; eg < 2; ++eg) {
        const int p = ep[eg];
        const int r = p >> 14, c = p & 16383;
        const float* up = U + (size_t)r * 128;
        const float* vp = V + (size_t)c * 128;

        // ---- h A-fragments in registers: h = sigmoid(U[r]+V[c]) ----
        short8 hA[4];
#pragma unroll
        for (int kk2 = 0; kk2 < 4; ++kk2) {
            const int k0 = kk2 * 32 + q * 8;
            const float4 u0 = *(const float4*)(up + k0);
            const float4 u1 = *(const float4*)(up + k0 + 4);
            const float4 v0 = *(const float4*)(vp + k0);
            const float4 v1 = *(const float4*)(vp + k0 + 4);
            short8 ha;
            ha[0] = f2bf(sigmoidf_(u0.x + v0.x));
            ha[1] = f2bf(sigmoidf_(u0.y + v0.y));
            ha[2] = f2bf(sigmoidf_(u0.z + v0.z));
            ha[3] = f2bf(sigmoidf_(u0.w + v0.w));
            ha[4] = f2bf(sigmoidf_(u1.x + v1.x));
            ha[5] = f2bf(sigmoidf_(u1.y + v1.y));
            ha[6] = f2bf(sigmoidf_(u1.z + v1.z));
            ha[7] = f2bf(sigmoidf_(u1.w + v1.w));
            hA[kk2] = ha;
        }

        // ---- GEMM2: msg[16 e][128 m] = h(A, regs) x W2(B, LDS), K=128 ----
        floatx4 acc2[8];
#pragma unroll
        for (int i = 0; i < 8; ++i) acc2[i] = (floatx4)(0.f);
#pragma unroll
        for (int kk2 = 0; kk2 < 4; ++kk2) {
#pragma unroll
            for (int mt = 0; mt < 8; ++mt) {
                const int m = mt * 16 + l15;
                const int idx = m * 128 + ((kk2 * 32 + q * 8) ^ ((m & 7) << 3));
                short8 wfr = *(const short8*)(wlds + idx);
                acc2[mt] = __builtin_amdgcn_mfma_f32_16x16x32_bf16(
                    hA[kk2], wfr, acc2[mt], 0, 0, 0);
            }
        }

        // ---- softsign + in-register 16-edge reduction + coalesced scatter ----
        const int n0 = __shfl(r, 0);
        const bool uni = (bool)__all(r == n0);
        if (uni) {
#pragma unroll
            for (int mt = 0; mt < 8; ++mt) {
                const float b = biasb[mt * 16 + l15];
                float s = softsignf_(acc2[mt][0] + b) + softsignf_(acc2[mt][1] + b)
                        + softsignf_(acc2[mt][2] + b) + softsignf_(acc2[mt][3] + b);
                s += __shfl_xor(s, 16);
                s += __shfl_xor(s, 32);
                if (q == 0) atomicAdd(&agg[(size_t)n0 * 128 + mt * 16 + l15], s);
            }
        } else {
            int nd[4];
#pragma unroll
            for (int rr = 0; rr < 4; ++rr) nd[rr] = __shfl(r, q * 4 + rr);
#pragma unroll
            for (int mt = 0; mt < 8; ++mt) {
                const float b = biasb[mt * 16 + l15];
                float run = 0.f;
#pragma unroll
                for (int rr = 0; rr < 4; ++rr) {
                    run += softsignf_(acc2[mt][rr] + b);
                    if (rr == 3 || nd[rr + 1] != nd[rr]) {
                        atomicAdd(&agg[(size_t)nd[rr] * 128 + mt * 16 + l15], run);
                        run = 0.f;
                    }
                }
            }
        }
    }
}

// ---------- node kernel ----------
// NOTE: agg aliases out (d_out). Node n reads agg row n (GEMM1 phase) strictly
// before writing out row n (epilogue); waves own disjoint node ranges.
__global__ __launch_bounds__(256) void node_kernel(
    const float* __restrict__ feat,
    const float* agg,
    const float* __restrict__ temb,
    const short* __restrict__ Wf1T,
    const float* __restrict__ bf1v,
    const short* __restrict__ Wf2T,
    const float* __restrict__ bf2v,
    float* out)
{
    __shared__ __align__(16) short gbuf[4][16][128];
    const int tid = threadIdx.x;
    const int w = tid >> 6, l = tid & 63;
    const int l15 = l & 15, q = l >> 4;
    const int nbase = blockIdx.x * 64 + w * 16;
    if (nbase >= NN) return;

    const int nA = nbase + l15;
    const float* p0 = feat + (size_t)nA * 128 + q * 8;
    const float* p1 = agg + (size_t)nA * 128 + q * 8;
    const float* p2 = temb + (size_t)nA * 128 + q * 8;

    floatx4 acc[8];
#pragma unroll
    for (int i = 0; i < 8; ++i) acc[i] = (floatx4)(0.f);

#pragma unroll
    for (int kk = 0; kk < 12; ++kk) {                   // K = 384 = 12 x 32
        const float* ap = (kk < 4) ? (p0 + kk * 32)
                        : (kk < 8) ? (p1 + (kk - 4) * 32)
                                   : (p2 + (kk - 8) * 32);
        const float4 a0 = *(const float4*)(ap);
        const float4 a1 = *(const float4*)(ap + 4);
        short8 af;
        af[0] = f2bf(sigmoidf_(a0.x)); af[1] = f2bf(sigmoidf_(a0.y));
        af[2] = f2bf(sigmoidf_(a0.z)); af[3] = f2bf(sigmoidf_(a0.w));
        af[4] = f2bf(sigmoidf_(a1.x)); af[5] = f2bf(sigmoidf_(a1.y));
        af[6] = f2bf(sigmoidf_(a1.z)); af[7] = f2bf(sigmoidf_(a1.w));
        const int krow = kk * 32 + q * 8;
#pragma unroll
        for (int ct = 0; ct < 8; ++ct) {
            const int col = ct * 16 + l15;
            short8 bf = *(const short8*)(Wf1T + col * 384 + krow);
            acc[ct] = __builtin_amdgcn_mfma_f32_16x16x32_bf16(af, bf, acc[ct], 0, 0, 0);
        }
    }

#pragma unroll
    for (int ct = 0; ct < 8; ++ct) {
        const int col = ct * 16 + l15;
        const float b = bf1v[col];
#pragma unroll
        for (int r = 0; r < 4; ++r) {
            gbuf[w][q * 4 + r][col] = f2bf(sigmoidf_(acc[ct][r] + b));
        }
    }

    floatx4 acc2[8];
#pragma unroll
    for (int i = 0; i < 8; ++i) acc2[i] = (floatx4)(0.f);
#pragma unroll
    for (int kk = 0; kk < 4; ++kk) {
        const int krow = kk * 32 + q * 8;
        short8 af = *(const short8*)(&gbuf[w][l15][krow]);
#pragma unroll
        for (int ct = 0; ct < 8; ++ct) {
            const int col = ct * 16 + l15;
            short8 bf = *(const short8*)(Wf2T + col * 128 + krow);
            acc2[ct] = __builtin_amdgcn_mfma_f32_16x16x32_bf16(af, bf, acc2[ct], 0, 0, 0);
        }
    }

#pragma unroll
    for (int ct = 0; ct < 8; ++ct) {
        const int col = ct * 16 + l15;
        const float b = bf2v[col];
#pragma unroll
        for (int r = 0; r < 4; ++r) {
            const int node = nbase + q * 4 + r;
            out[(size_t)node * 128 + col] = softsignf_(acc2[ct][r] + b);
        }
    }
}

extern "C" void kernel_launch(void* const* d_in, const int* in_sizes, int n_in,
                              void* d_out, int out_size, void* d_ws, size_t ws_size,
                              hipStream_t stream)
{
    const float* feat = (const float*)d_in[0];
    const int* rows = (const int*)d_in[1];
    const int* cols = (const int*)d_in[2];
    const float* temb = (const float*)d_in[3];
    const float* Wm1 = (const float*)d_in[4];
    const float* bm1 = (const float*)d_in[5];
    const float* Wm2 = (const float*)d_in[6];
    const float* bm2 = (const float*)d_in[7];
    const float* Wf1 = (const float*)d_in[8];
    const float* bf1 = (const float*)d_in[9];
    const float* Wf2 = (const float*)d_in[10];
    const float* bf2 = (const float*)d_in[11];
    float* out = (float*)d_out;
    float* agg = (float*)d_out;   // aliased: edge scatters here, node reads row n before writing row n

    // Workspace layout (16B-aligned):
    //   U      f32  [10000][128]      5,120,000 B   @ 0
    //   V      f32  [10000][128]      5,120,000 B   @ 5,120,000
    //   WuvT   bf16 [256][128]           65,536 B   @ 10,240,000
    //   W2s    bf16 [128][128] swz       32,768 B   @ 10,305,536
    //   Wf1T   bf16 [128][384]           98,304 B   @ 10,338,304
    //   Wf2T   bf16 [128][128]           32,768 B   @ 10,436,608
    //   e1     i32  [NE] packed       2,560,000 B   @ 10,469,376
    //   counts i32  [NN]                 40,000 B   @ 13,029,376
    //   nodeoff i32 [NN]                 40,000 B   @ 13,069,376
    char* ws = (char*)d_ws;
    float* U     = (float*)ws;
    float* V     = (float*)(ws + 5120000);
    short* WuvT  = (short*)(ws + 10240000);
    short* W2s   = (short*)(ws + 10305536);
    short* Wf1T  = (short*)(ws + 10338304);
    short* Wf2T  = (short*)(ws + 10436608);
    int* e1      = (int*)(ws + 10469376);
    int* counts  = (int*)(ws + 13029376);
    int* nodeoff = (int*)(ws + 13069376);
    const size_t NEEDED = 13109376;

    if (ws_size >= NEEDED) {
        hipMemsetAsync(counts, 0, NN * sizeof(int), stream);
        prep_all<<<4198, 256, 0, stream>>>(rows, Wm1, Wm2, Wf1, Wf2,
                                           agg, WuvT, W2s, Wf1T, Wf2T, counts);
        uv_kernel<<<157, 256, 0, stream>>>(feat, WuvT, bm1, U, V);
        scan_kernel<<<1, 1024, 0, stream>>>(counts, nodeoff);
        reorder_kernel<<<(NE + 255) / 256, 256, 0, stream>>>(rows, cols, nodeoff, e1);
    } else {
        prep_all<<<4198, 256, 0, stream>>>(rows, Wm1, Wm2, Wf1, Wf2,
                                           agg, WuvT, W2s, Wf1T, Wf2T, counts);
        uv_kernel<<<157, 256, 0, stream>>>(feat, WuvT, bm1, U, V);
        pack_edges<<<(NE + 255) / 256, 256, 0, stream>>>(rows, cols, e1);
    }

    edge_kernel<<<NE / 512, 1024, 0, stream>>>(U, V, e1, W2s, bm2, agg);
    node_kernel<<<(NN + 63) / 64, 256, 0, stream>>>(feat, agg, temb, Wf1T, bf1, Wf2T, bf2, out);
}

// Round 11
// 226.626 us; speedup vs baseline: 1.4014x; 1.0139x over previous
//
#include <hip/hip_runtime.h>
#include <hip/hip_bf16.h>

// Graph message-passing layer, bf16 MFMA implementation, v11.
// vs v10: (1) all f32->bf16 conversions use native __float2bfloat16 (RNE HW
// instruction; manual bit-RNE blocked compiler packing); (2) uv_kernel and
// node_kernel re-gridded to 1-wave blocks x 625 (was 157x4 waves -> 99 idle CUs).
// Structure otherwise identical to v10 (verified passing).
// N=10000 nodes, E=640000 edges, F=M=O=128.

#define NN 10000
#define NE 640000

typedef __attribute__((ext_vector_type(8))) short short8;
typedef __attribute__((ext_vector_type(4))) short short4v;
typedef __attribute__((ext_vector_type(4))) float floatx4;

__device__ __forceinline__ short bfc(float f) {
    __hip_bfloat16 h = __float2bfloat16(f);
    return *reinterpret_cast<short*>(&h);
}

__device__ __forceinline__ float sigmoidf_(float x) {
    return __builtin_amdgcn_rcpf(1.f + __expf(-x));
}
__device__ __forceinline__ float softsignf_(float x) {
    return x * __builtin_amdgcn_rcpf(1.f + fabsf(x));
}

// ---------- fused prep kernel ----------
// partitions: [0,1250) agg(=d_out) zero | [1250,3750) hist | [3750,3878) WuvT
// | [3878,3942) W2 swz | [3942,4134) Wf1T | [4134,4198) Wf2T
__global__ __launch_bounds__(256) void prep_all(
    const int* __restrict__ rows,
    const float* __restrict__ Wm1, const float* __restrict__ Wm2,
    const float* __restrict__ Wf1, const float* __restrict__ Wf2,
    float* __restrict__ agg, short* __restrict__ WuvT, short* __restrict__ W2s,
    short* __restrict__ Wf1T, short* __restrict__ Wf2T, int* __restrict__ counts)
{
    const int bid = blockIdx.x, tid = threadIdx.x;
    if (bid < 1250) {                       // zero agg: 1,280,000 f32 = 320,000 f4
        int i = bid * 256 + tid;
        ((float4*)agg)[i] = make_float4(0.f, 0.f, 0.f, 0.f);
    } else if (bid < 3750) {                // histogram of rows
        int e = (bid - 1250) * 256 + tid;   // 640000, exact
        atomicAdd(&counts[rows[e]], 1);
    } else if (bid < 3878) {                // WuvT[256][128]: c<128 -> W1a^T, else W1b^T
        int i = (bid - 3750) * 256 + tid;   // 32768, exact
        int c = i >> 7, k = i & 127;
        WuvT[i] = bfc(Wm1[(k + ((c >> 7) << 7)) * 128 + (c & 127)]);
    } else if (bid < 3942) {                // Wm2 [128][128] -> swz [m][k^((m&7)<<3)]
        int i = (bid - 3878) * 256 + tid;   // 16384, exact
        int m = i >> 7, k = i & 127;
        W2s[m * 128 + (k ^ ((m & 7) << 3))] = bfc(Wm2[k * 128 + m]);
    } else if (bid < 4134) {                // Wf1 [384][128] -> T [128][384]
        int i = (bid - 3942) * 256 + tid;   // 49152, exact
        int c = i / 384, k = i - c * 384;
        Wf1T[i] = bfc(Wf1[k * 128 + c]);
    } else {                                // Wf2 [128][128] -> T
        int i = (bid - 4134) * 256 + tid;   // 16384, exact
        int c = i >> 7, k = i & 127;
        Wf2T[i] = bfc(Wf2[k * 128 + c]);
    }
}

// ---------- U|V kernel: [10000,128] x [128,256], 1 wave / 16 nodes ----------
__global__ __launch_bounds__(64) void uv_kernel(
    const float* __restrict__ feat,
    const short* __restrict__ WuvT,   // [256 c][128 k] bf16
    const float* __restrict__ bm1,
    float* __restrict__ U, float* __restrict__ V)
{
    const int l = threadIdx.x;
    const int l15 = l & 15, q = l >> 4;
    const int nbase = blockIdx.x * 16;            // grid 625, exact

    const float* p0 = feat + (size_t)(nbase + l15) * 128;

    floatx4 acc[16];
#pragma unroll
    for (int i = 0; i < 16; ++i) acc[i] = (floatx4)(0.f);

#pragma unroll
    for (int kk = 0; kk < 4; ++kk) {                    // K = 128
        const int krow = kk * 32 + q * 8;
        const float4 a0 = *(const float4*)(p0 + krow);
        const float4 a1 = *(const float4*)(p0 + krow + 4);
        short8 af;
        af[0] = bfc(a0.x); af[1] = bfc(a0.y); af[2] = bfc(a0.z); af[3] = bfc(a0.w);
        af[4] = bfc(a1.x); af[5] = bfc(a1.y); af[6] = bfc(a1.z); af[7] = bfc(a1.w);
#pragma unroll
        for (int ct = 0; ct < 16; ++ct) {
            const int c = ct * 16 + l15;
            short8 bf = *(const short8*)(WuvT + c * 128 + krow);
            acc[ct] = __builtin_amdgcn_mfma_f32_16x16x32_bf16(af, bf, acc[ct], 0, 0, 0);
        }
    }

#pragma unroll
    for (int ct = 0; ct < 8; ++ct) {
        const int c = ct * 16 + l15;
        const float b = bm1[c];
#pragma unroll
        for (int r = 0; r < 4; ++r)
            U[(size_t)(nbase + q * 4 + r) * 128 + c] = acc[ct][r] + b;
    }
#pragma unroll
    for (int ct = 8; ct < 16; ++ct) {
        const int c = ct * 16 + l15 - 128;
#pragma unroll
        for (int r = 0; r < 4; ++r)
            V[(size_t)(nbase + q * 4 + r) * 128 + c] = acc[ct][r];
    }
}

// exclusive prefix sum over counts[NN], single 1024-thread block
__global__ __launch_bounds__(1024) void scan_kernel(const int* __restrict__ counts,
                                                    int* __restrict__ nodeoff) {
    __shared__ int buf[1024];
    const int tid = threadIdx.x;
    const int base = tid * 10;                 // 1024*10 >= NN
    int loc[10]; int s = 0;
#pragma unroll
    for (int i = 0; i < 10; ++i) {
        int idx = base + i;
        int c = (idx < NN) ? counts[idx] : 0;
        loc[i] = s; s += c;
    }
    buf[tid] = s;
    __syncthreads();
    for (int off = 1; off < 1024; off <<= 1) {   // Hillis-Steele inclusive
        int v = (tid >= off) ? buf[tid - off] : 0;
        __syncthreads();
        buf[tid] += v;
        __syncthreads();
    }
    int pref = (tid == 0) ? 0 : buf[tid - 1];
#pragma unroll
    for (int i = 0; i < 10; ++i) {
        int idx = base + i;
        if (idx < NN) nodeoff[idx] = pref + loc[i];
    }
}

// reorder; nodeoff doubles as the cursor (destroyed here, dead afterward)
__global__ void reorder_kernel(const int* __restrict__ rows, const int* __restrict__ cols,
                               int* __restrict__ nodeoff, int* __restrict__ e1) {
    int e = blockIdx.x * 256 + threadIdx.x;
    if (e >= NE) return;
    int r = rows[e];
    int p = atomicAdd(&nodeoff[r], 1);
    e1[p] = (r << 14) | cols[e];
}

// non-sorted fallback if workspace is too small
__global__ void pack_edges(const int* __restrict__ rows, const int* __restrict__ cols,
                           int* __restrict__ e1) {
    int e = blockIdx.x * 256 + threadIdx.x;
    if (e < NE) e1[e] = (rows[e] << 14) | cols[e];
}

// ---------- edge kernel ----------
// 1024 threads = 16 waves; 32 edges/wave (2 serial groups of 16); 512 edges/block.
__global__ __launch_bounds__(1024, 4) void edge_kernel(
    const float* __restrict__ U,
    const float* __restrict__ V,
    const int* __restrict__ e1,       // sorted packed (r<<14)|c
    const short* __restrict__ W2s,    // swizzled [128][128]
    const float* __restrict__ bm2,
    float* agg)
{
    __shared__ __align__(16) short wlds[16384];   // 32 KB: W2
    __shared__ float biasb[128];                  // bm2
    const int tid = threadIdx.x;
    const int w = tid >> 6, l = tid & 63;
    const int q = l >> 4, l15 = l & 15;
    const int ebase = blockIdx.x * 512 + w * 32;

    // prefetch packed edges (hides under W2 staging)
    int ep[2];
    ep[0] = e1[ebase + l15];
    ep[1] = e1[ebase + 16 + l15];

    // stage W2 (linear copy; source is pre-swizzled)
    {
        const short8* gs = (const short8*)W2s;
        short8* ls = (short8*)wlds;
        ls[tid] = gs[tid];
        ls[1024 + tid] = gs[1024 + tid];
        if (tid < 128) biasb[tid] = bm2[tid];
    }
    __syncthreads();

#pragma unroll
    for (int eg = 0; eg < 2; ++eg) {
        const int p = ep[eg];
        const int r = p >> 14, c = p & 16383;
        const float* up = U + (size_t)r * 128;
        const float* vp = V + (size_t)c * 128;

        // ---- h A-fragments in registers: h = sigmoid(U[r]+V[c]) ----
        short8 hA[4];
#pragma unroll
        for (int kk2 = 0; kk2 < 4; ++kk2) {
            const int k0 = kk2 * 32 + q * 8;
            const float4 u0 = *(const float4*)(up + k0);
            const float4 u1 = *(const float4*)(up + k0 + 4);
            const float4 v0 = *(const float4*)(vp + k0);
            const float4 v1 = *(const float4*)(vp + k0 + 4);
            short8 ha;
            ha[0] = bfc(sigmoidf_(u0.x + v0.x));
            ha[1] = bfc(sigmoidf_(u0.y + v0.y));
            ha[2] = bfc(sigmoidf_(u0.z + v0.z));
            ha[3] = bfc(sigmoidf_(u0.w + v0.w));
            ha[4] = bfc(sigmoidf_(u1.x + v1.x));
            ha[5] = bfc(sigmoidf_(u1.y + v1.y));
            ha[6] = bfc(sigmoidf_(u1.z + v1.z));
            ha[7] = bfc(sigmoidf_(u1.w + v1.w));
            hA[kk2] = ha;
        }

        // ---- GEMM2: msg[16 e][128 m] = h(A, regs) x W2(B, LDS), K=128 ----
        floatx4 acc2[8];
#pragma unroll
        for (int i = 0; i < 8; ++i) acc2[i] = (floatx4)(0.f);
#pragma unroll
        for (int kk2 = 0; kk2 < 4; ++kk2) {
#pragma unroll
            for (int mt = 0; mt < 8; ++mt) {
                const int m = mt * 16 + l15;
                const int idx = m * 128 + ((kk2 * 32 + q * 8) ^ ((m & 7) << 3));
                short8 wfr = *(const short8*)(wlds + idx);
                acc2[mt] = __builtin_amdgcn_mfma_f32_16x16x32_bf16(
                    hA[kk2], wfr, acc2[mt], 0, 0, 0);
            }
        }

        // ---- softsign + in-register 16-edge reduction + coalesced scatter ----
        const int n0 = __shfl(r, 0);
        const bool uni = (bool)__all(r == n0);
        if (uni) {
#pragma unroll
            for (int mt = 0; mt < 8; ++mt) {
                const float b = biasb[mt * 16 + l15];
                float s = softsignf_(acc2[mt][0] + b) + softsignf_(acc2[mt][1] + b)
                        + softsignf_(acc2[mt][2] + b) + softsignf_(acc2[mt][3] + b);
                s += __shfl_xor(s, 16);
                s += __shfl_xor(s, 32);
                if (q == 0) atomicAdd(&agg[(size_t)n0 * 128 + mt * 16 + l15], s);
            }
        } else {
            int nd[4];
#pragma unroll
            for (int rr = 0; rr < 4; ++rr) nd[rr] = __shfl(r, q * 4 + rr);
#pragma unroll
            for (int mt = 0; mt < 8; ++mt) {
                const float b = biasb[mt * 16 + l15];
                float run = 0.f;
#pragma unroll
                for (int rr = 0; rr < 4; ++rr) {
                    run += softsignf_(acc2[mt][rr] + b);
                    if (rr == 3 || nd[rr + 1] != nd[rr]) {
                        atomicAdd(&agg[(size_t)nd[rr] * 128 + mt * 16 + l15], run);
                        run = 0.f;
                    }
                }
            }
        }
    }
}

// ---------- node kernel: 1 wave / 16 nodes ----------
// NOTE: agg aliases out (d_out). Node n reads agg row n strictly before
// writing out row n; waves own disjoint node ranges.
__global__ __launch_bounds__(64) void node_kernel(
    const float* __restrict__ feat,
    const float* agg,
    const float* __restrict__ temb,
    const short* __restrict__ Wf1T,
    const float* __restrict__ bf1v,
    const short* __restrict__ Wf2T,
    const float* __restrict__ bf2v,
    float* out)
{
    __shared__ __align__(16) short gbuf[16][128];
    const int l = threadIdx.x;
    const int l15 = l & 15, q = l >> 4;
    const int nbase = blockIdx.x * 16;            // grid 625, exact

    const int nA = nbase + l15;
    const float* p0 = feat + (size_t)nA * 128 + q * 8;
    const float* p1 = agg + (size_t)nA * 128 + q * 8;
    const float* p2 = temb + (size_t)nA * 128 + q * 8;

    floatx4 acc[8];
#pragma unroll
    for (int i = 0; i < 8; ++i) acc[i] = (floatx4)(0.f);

#pragma unroll
    for (int kk = 0; kk < 12; ++kk) {                   // K = 384 = 12 x 32
        const float* ap = (kk < 4) ? (p0 + kk * 32)
                        : (kk < 8) ? (p1 + (kk - 4) * 32)
                                   : (p2 + (kk - 8) * 32);
        const float4 a0 = *(const float4*)(ap);
        const float4 a1 = *(const float4*)(ap + 4);
        short8 af;
        af[0] = bfc(sigmoidf_(a0.x)); af[1] = bfc(sigmoidf_(a0.y));
        af[2] = bfc(sigmoidf_(a0.z)); af[3] = bfc(sigmoidf_(a0.w));
        af[4] = bfc(sigmoidf_(a1.x)); af[5] = bfc(sigmoidf_(a1.y));
        af[6] = bfc(sigmoidf_(a1.z)); af[7] = bfc(sigmoidf_(a1.w));
        const int krow = kk * 32 + q * 8;
#pragma unroll
        for (int ct = 0; ct < 8; ++ct) {
            const int col = ct * 16 + l15;
            short8 bf = *(const short8*)(Wf1T + col * 384 + krow);
            acc[ct] = __builtin_amdgcn_mfma_f32_16x16x32_bf16(af, bf, acc[ct], 0, 0, 0);
        }
    }

#pragma unroll
    for (int ct = 0; ct < 8; ++ct) {
        const int col = ct * 16 + l15;
        const float b = bf1v[col];
#pragma unroll
        for (int r = 0; r < 4; ++r) {
            gbuf[q * 4 + r][col] = bfc(sigmoidf_(acc[ct][r] + b));
        }
    }

    floatx4 acc2[8];
#pragma unroll
    for (int i = 0; i < 8; ++i) acc2[i] = (floatx4)(0.f);
#pragma unroll
    for (int kk = 0; kk < 4; ++kk) {
        const int krow = kk * 32 + q * 8;
        short8 af = *(const short8*)(&gbuf[l15][krow]);
#pragma unroll
        for (int ct = 0; ct < 8; ++ct) {
            const int col = ct * 16 + l15;
            short8 bf = *(const short8*)(Wf2T + col * 128 + krow);
            acc2[ct] = __builtin_amdgcn_mfma_f32_16x16x32_bf16(af, bf, acc2[ct], 0, 0, 0);
        }
    }

#pragma unroll
    for (int ct = 0; ct < 8; ++ct) {
        const int col = ct * 16 + l15;
        const float b = bf2v[col];
#pragma unroll
        for (int r = 0; r < 4; ++r) {
            const int node = nbase + q * 4 + r;
            out[(size_t)node * 128 + col] = softsignf_(acc2[ct][r] + b);
        }
    }
}

extern "C" void kernel_launch(void* const* d_in, const int* in_sizes, int n_in,
                              void* d_out, int out_size, void* d_ws, size_t ws_size,
                              hipStream_t stream)
{
    const float* feat = (const float*)d_in[0];
    const int* rows = (const int*)d_in[1];
    const int* cols = (const int*)d_in[2];
    const float* temb = (const float*)d_in[3];
    const float* Wm1 = (const float*)d_in[4];
    const float* bm1 = (const float*)d_in[5];
    const float* Wm2 = (const float*)d_in[6];
    const float* bm2 = (const float*)d_in[7];
    const float* Wf1 = (const float*)d_in[8];
    const float* bf1 = (const float*)d_in[9];
    const float* Wf2 = (const float*)d_in[10];
    const float* bf2 = (const float*)d_in[11];
    float* out = (float*)d_out;
    float* agg = (float*)d_out;   // aliased: edge scatters here, node reads row n before writing row n

    // Workspace layout (16B-aligned):
    //   U      f32  [10000][128]      5,120,000 B   @ 0
    //   V      f32  [10000][128]      5,120,000 B   @ 5,120,000
    //   WuvT   bf16 [256][128]           65,536 B   @ 10,240,000
    //   W2s    bf16 [128][128] swz       32,768 B   @ 10,305,536
    //   Wf1T   bf16 [128][384]           98,304 B   @ 10,338,304
    //   Wf2T   bf16 [128][128]           32,768 B   @ 10,436,608
    //   e1     i32  [NE] packed       2,560,000 B   @ 10,469,376
    //   counts i32  [NN]                 40,000 B   @ 13,029,376
    //   nodeoff i32 [NN]                 40,000 B   @ 13,069,376
    char* ws = (char*)d_ws;
    float* U     = (float*)ws;
    float* V     = (float*)(ws + 5120000);
    short* WuvT  = (short*)(ws + 10240000);
    short* W2s   = (short*)(ws + 10305536);
    short* Wf1T  = (short*)(ws + 10338304);
    short* Wf2T  = (short*)(ws + 10436608);
    int* e1      = (int*)(ws + 10469376);
    int* counts  = (int*)(ws + 13029376);
    int* nodeoff = (int*)(ws + 13069376);
    const size_t NEEDED = 13109376;

    if (ws_size >= NEEDED) {
        hipMemsetAsync(counts, 0, NN * sizeof(int), stream);
        prep_all<<<4198, 256, 0, stream>>>(rows, Wm1, Wm2, Wf1, Wf2,
                                           agg, WuvT, W2s, Wf1T, Wf2T, counts);
        uv_kernel<<<625, 64, 0, stream>>>(feat, WuvT, bm1, U, V);
        scan_kernel<<<1, 1024, 0, stream>>>(counts, nodeoff);
        reorder_kernel<<<(NE + 255) / 256, 256, 0, stream>>>(rows, cols, nodeoff, e1);
    } else {
        prep_all<<<4198, 256, 0, stream>>>(rows, Wm1, Wm2, Wf1, Wf2,
                                           agg, WuvT, W2s, Wf1T, Wf2T, counts);
        uv_kernel<<<625, 64, 0, stream>>>(feat, WuvT, bm1, U, V);
        pack_edges<<<(NE + 255) / 256, 256, 0, stream>>>(rows, cols, e1);
    }

    edge_kernel<<<NE / 512, 1024, 0, stream>>>(U, V, e1, W2s, bm2, agg);
    node_kernel<<<625, 64, 0, stream>>>(feat, agg, temb, Wf1T, bf1, Wf2T, bf2, out);
}